// Round 4
// baseline (671.650 us; speedup 1.0000x reference)
//
#include <hip/hip_runtime.h>

// Problem constants
#define N_NODES 20000
#define N_ATTRS 5000
#define IN_F    512
#define OUT_F   128
#define NK      160           // ksteps of 32 attrs (5120 padded)
#define NSS     80            // supersteps (2 ksteps each)
#define WH2_PAD 5376          // wh2 allocation incl. pad
#define NEGBIG  -1e30f        // wh2 pad: exp2 underflows to 0 -> self-masking tail
#define LOG2E   1.4426950408889634f

typedef _Float16 f16x8 __attribute__((ext_vector_type(8)));
typedef float    f32x4 __attribute__((ext_vector_type(4)));
typedef int      i32x4 __attribute__((ext_vector_type(4)));

__device__ __forceinline__ float fast_exp2(float x) {
    return __builtin_amdgcn_exp2f(x);
}

// async global->LDS DMA, 16 B per lane. LDS dest = wave-uniform base + lane*16.
// NOTE: the GLOBAL source address is per-lane and must include lane*16.
__device__ __forceinline__ void async16(void* lds_dst, const void* gsrc) {
    __builtin_amdgcn_global_load_lds(
        (const __attribute__((address_space(1))) unsigned int*)gsrc,
        (__attribute__((address_space(3))) unsigned int*)lds_dst, 16, 0, 0);
}

// ---------------------------------------------------------------------------
// Kernel 1: Wa1 = W @ a[:128], Wa2 = W @ a[128:], pre-scaled by log2(e);
// repack W into f16 MFMA B-fragment order.
// ---------------------------------------------------------------------------
__global__ __launch_bounds__(256) void prep_kernel(
    const float* __restrict__ W, const float* __restrict__ a,
    float* __restrict__ Wa1, float* __restrict__ Wa2, _Float16* __restrict__ Wp) {
    int gt = blockIdx.x * blockDim.x + threadIdx.x;
    if (gt < IN_F) {
        int k = gt;
        float s1 = 0.f, s2 = 0.f;
        for (int f = 0; f < OUT_F; ++f) {
            float w = W[k * OUT_F + f];
            s1 += w * a[f];
            s2 += w * a[OUT_F + f];
        }
        Wa1[k] = s1 * LOG2E;
        Wa2[k] = s2 * LOG2E;
    }
    for (int idx = gt; idx < IN_F * OUT_F; idx += gridDim.x * blockDim.x) {
        int j    = idx & 7;
        int lane = (idx >> 3) & 63;
        int nb   = (idx >> 9) & 7;
        int kb   = idx >> 12;
        int k = kb * 32 + (lane >> 4) * 8 + j;
        int n = nb * 16 + (lane & 15);
        Wp[idx] = (_Float16)W[k * OUT_F + n];
    }
}

// ---------------------------------------------------------------------------
// Kernel 2: wh1[i] = node_emb[i] . Wa1 ; wh2[j] = attr_emb[j] . Wa2
// ---------------------------------------------------------------------------
__global__ __launch_bounds__(256) void wh_kernel(
    const float* __restrict__ node_emb, const float* __restrict__ attr_emb,
    const float* __restrict__ Wa1, const float* __restrict__ Wa2,
    float* __restrict__ wh1, float* __restrict__ wh2) {
    int wave = threadIdx.x >> 6, lane = threadIdx.x & 63;
    int r = blockIdx.x * 4 + wave;   // grid = 6250 -> r in [0, 25000)
    const float* src;
    const float* vec;
    float* dst;
    if (r < N_NODES) {
        src = node_emb + (size_t)r * IN_F; vec = Wa1; dst = wh1 + r;
    } else {
        int r2 = r - N_NODES;
        src = attr_emb + (size_t)r2 * IN_F; vec = Wa2; dst = wh2 + r2;
    }
    float4 ra = *reinterpret_cast<const float4*>(src + lane * 8);
    float4 rb = *reinterpret_cast<const float4*>(src + lane * 8 + 4);
    const float* vp = vec + lane * 8;
    float s = ra.x * vp[0] + ra.y * vp[1] + ra.z * vp[2] + ra.w * vp[3]
            + rb.x * vp[4] + rb.y * vp[5] + rb.z * vp[6] + rb.w * vp[7];
#pragma unroll
    for (int off = 1; off < 64; off <<= 1) s += __shfl_xor(s, off, 64);
    if (lane == 0) *dst = s;
}

// ---------------------------------------------------------------------------
// Kernel 2b: maxwh2 = max_j wh2[j]; fill wh2 pad with NEGBIG. single block.
// ---------------------------------------------------------------------------
__global__ __launch_bounds__(256) void max_kernel(
    float* __restrict__ wh2, float* __restrict__ maxp) {
    __shared__ float red[4];
    int t = threadIdx.x;
    float m = -1e30f;
    for (int j = t; j < N_ATTRS; j += 256) m = fmaxf(m, wh2[j]);
    for (int j = N_ATTRS + t; j < WH2_PAD; j += 256) wh2[j] = NEGBIG;
#pragma unroll
    for (int off = 1; off < 64; off <<= 1) m = fmaxf(m, __shfl_xor(m, off, 64));
    int wave = t >> 6, lane = t & 63;
    if (lane == 0) red[wave] = m;
    __syncthreads();
    if (t == 0) *maxp = fmaxf(fmaxf(red[0], red[1]), fmaxf(red[2], red[3]));
}

// ---------------------------------------------------------------------------
// Kernel 3: V = attr_emb @ W  [5120(pad) x 128] f16 in B-fragment order.
// grid 320 x 64: one wave per block -> spreads over all 256 CUs.
// ---------------------------------------------------------------------------
__global__ __launch_bounds__(64) void attr_h_kernel(
    const float* __restrict__ attr_emb, const _Float16* __restrict__ Wp,
    _Float16* __restrict__ Vp) {
    int lane = threadIdx.x & 63;
    int m = lane & 15, quad = lane >> 4;
    int j0 = blockIdx.x * 16;               // grid = 320 -> j0 in [0, 5120)
    int j = j0 + m;
    bool valid = j < N_ATTRS;
    f32x4 acc[8];
#pragma unroll
    for (int nb = 0; nb < 8; ++nb)
#pragma unroll
        for (int t = 0; t < 4; ++t) acc[nb][t] = 0.f;
    const float* arow = attr_emb + (size_t)j * IN_F;
    for (int kk = 0; kk < IN_F / 32; ++kk) {
        f16x8 afrag;
        if (valid) {
            float4 ra = *reinterpret_cast<const float4*>(arow + kk * 32 + quad * 8);
            float4 rb = *reinterpret_cast<const float4*>(arow + kk * 32 + quad * 8 + 4);
            afrag[0] = (_Float16)ra.x; afrag[1] = (_Float16)ra.y;
            afrag[2] = (_Float16)ra.z; afrag[3] = (_Float16)ra.w;
            afrag[4] = (_Float16)rb.x; afrag[5] = (_Float16)rb.y;
            afrag[6] = (_Float16)rb.z; afrag[7] = (_Float16)rb.w;
        } else {
#pragma unroll
            for (int t = 0; t < 8; ++t) afrag[t] = (_Float16)0.f;
        }
        const _Float16* wbase = Wp + (size_t)(kk * 8) * 64 * 8;
#pragma unroll
        for (int nb = 0; nb < 8; ++nb) {
            f16x8 bfrag;
            __builtin_memcpy(&bfrag, wbase + (nb * 64 + lane) * 8, 16);
            acc[nb] = __builtin_amdgcn_mfma_f32_16x16x32_f16(afrag, bfrag, acc[nb], 0, 0, 0);
        }
    }
#pragma unroll
    for (int nb = 0; nb < 8; ++nb) {
#pragma unroll
        for (int reg = 0; reg < 4; ++reg) {
            int jr = j0 + quad * 4 + reg;
            int n = nb * 16 + m;
            float v = (jr < N_ATTRS) ? acc[nb][reg] : 0.f;  // zero the K padding
            size_t idx = ((size_t)((jr >> 5) * 8 + nb) * 64 +
                          (((jr >> 3) & 3) * 16 + m)) * 8 + (jr & 7);
            Vp[idx] = (_Float16)v;
        }
    }
}

// ---------------------------------------------------------------------------
// Kernel 3b: pack feat (0/1 int32, 400 MB) -> fmask bits (12.8 MB).
// fmask[row][kk] where the CONTENT is kstep ko, stored pre-swizzled:
//   kk = (ko & ~31) | ((ko & 31) ^ (2*(row & 15) & 31))
// so attn can stage rows linearly into LDS (global_load_lds is linear-dest)
// and read word [m][k] at a bank-conflict-free swizzled index (rule: swizzle
// the source, keep LDS linear). XOR is an involution, so reading at the
// swizzled index recovers kstep k exactly.
// Pure stream: ~64 us at 6.3 TB/s.
// ---------------------------------------------------------------------------
__global__ __launch_bounds__(256) void pack_kernel(
    const int* __restrict__ feat, unsigned* __restrict__ fmask) {
    int u = blockIdx.x * 256 + threadIdx.x;     // grid 12500 -> u < 3.2M exact
    int row = u / 160;
    int kk  = u - row * 160;                    // stored position
    int ko  = (kk & ~31) | ((kk & 31) ^ ((2 * (row & 15)) & 31));  // source kstep
    unsigned bits = 0;
    if (ko < 156) {                             // attrs ko*32 .. ko*32+31 all valid
        const int* p = feat + (size_t)row * N_ATTRS + ko * 32;
#pragma unroll
        for (int q = 0; q < 8; ++q) {
            i32x4 v = *reinterpret_cast<const i32x4*>(p + q * 4);
            unsigned b = (v.x > 0 ? 1u : 0u) | (v.y > 0 ? 2u : 0u)
                       | (v.z > 0 ? 4u : 0u) | (v.w > 0 ? 8u : 0u);
            bits |= b << (q * 4);
        }
    } else if (ko == 156) {                     // attrs 4992..4999; rest masked by wh2 pad
        const int* p = feat + (size_t)row * N_ATTRS + 4992;
#pragma unroll
        for (int q = 0; q < 2; ++q) {
            i32x4 v = *reinterpret_cast<const i32x4*>(p + q * 4);
            unsigned b = (v.x > 0 ? 1u : 0u) | (v.y > 0 ? 2u : 0u)
                       | (v.z > 0 ? 4u : 0u) | (v.w > 0 ? 8u : 0u);
            bits |= b << (q * 4);
        }
    }                                           // ko in 157..159: bits = 0
    fmask[u] = bits;
}

// ---------------------------------------------------------------------------
// Kernel 4 (main): barrier-free compute over the bitmask.
//  - block = 32 rows (grid 625), 4 waves; wave w: rows (w>>1)*16..+15,
//    kstep parity w&1; superstep = 2 ksteps.
//  - fmask for the block's 32 rows (20 KB) staged into LDS ONCE (async DMA,
//    one barrier), pre-swizzled by pack_kernel -> per-superstep ds_read_b32
//    is bank-conflict-free (16 rows x stride 640 B would otherwise all hit
//    bank 0: 160 % 32 == 0).
//  - main loop: NO barriers, NO HBM traffic. Vp bfrags + wh2 from L2 via
//    named double buffers (bf0/bf1 -> static indices, no scratch), prefetch
//    distance 1; ~190 VALU cy/superstep/wave covers L2 latency.
// ---------------------------------------------------------------------------
__global__ __launch_bounds__(256, 2) void attn_kernel(
    const unsigned* __restrict__ fmask, const float* __restrict__ wh1,
    const float* __restrict__ wh2, const float* __restrict__ maxwh2,
    const _Float16* __restrict__ Vp, float* __restrict__ out) {
    __shared__ __align__(16) char lds[20480];   // fmask 32 rows x 640 B; epilogue overlay
    __shared__ float rsums[32];

    int wave = threadIdx.x >> 6, lane = threadIdx.x & 63;
    int m = lane & 15, quad = lane >> 4;
    int i0 = blockIdx.x * 32;
    int rg = (wave >> 1) * 16;         // row-group base (0 or 16)
    int half = wave & 1;               // kstep parity

    // ---- stage this block's fmask rows: 20480 B linear, 5 DMA per thread ----
    {
        const char* src = (const char*)(fmask + (size_t)i0 * 160);
#pragma unroll
        for (int q = 0; q < 5; ++q) {
            int off = q * 4096 + wave * 1024;
            // global source is PER-LANE: must carry lane*16 explicitly;
            // LDS dest adds lane*16 in hardware.
            async16(lds + off, src + off + lane * 16);
        }
    }

    float wh1i = wh1[i0 + rg + m];     // scaled by log2(e)
    float emax = wh1i + maxwh2[0];
    float Mi = fmaxf(emax, 0.2f * emax) - 12.f;   // f16 P in (0, 4096]

    f32x4 acc[8];
#pragma unroll
    for (int nb = 0; nb < 8; ++nb)
#pragma unroll
        for (int t = 0; t < 4; ++t) acc[nb][t] = 0.f;
    float s = 0.f;

    const unsigned* fml = (const unsigned*)lds;
    int swz = (2 * m) & 31;
    int fbase = (rg + m) * 160;

    // Vp/wh2 L2 double buffers (named -> static register indexing)
    f16x8  bf0[8], bf1[8];
    float4 w0a, w0b, w1a, w1b;
    auto loadV = [&](int ss, f16x8* bf, float4& wa, float4& wb) {
        const _Float16* vb = Vp + (size_t)(2 * ss + half) * 4096 + lane * 8;
#pragma unroll
        for (int nb = 0; nb < 8; ++nb)
            bf[nb] = *reinterpret_cast<const f16x8*>(vb + nb * 512);
        const float* wp = wh2 + ss * 64 + half * 32 + quad * 8;
        wa = *reinterpret_cast<const float4*>(wp);
        wb = *reinterpret_cast<const float4*>(wp + 4);
    };

    auto compute = [&](int ss, const f16x8* bf, float4 wa, float4 wb) {
        int k = 2 * ss + half;
        int kk = (k & ~31) | ((k & 31) ^ swz);
        unsigned fm = fml[fbase + kk] >> (quad * 8);
        float wv[8] = {wa.x, wa.y, wa.z, wa.w, wb.x, wb.y, wb.z, wb.w};
        f16x8 afrag;
#pragma unroll
        for (int t = 0; t < 8; ++t) {
            float e = wh1i + wv[t];                // pad attrs: e ~ -1e30
            float l = fmaxf(e, 0.2f * e);
            float p = fast_exp2(l - Mi);           // pad: exp2(-huge) = 0
            p = (fm & (1u << t)) ? p : 0.f;
            _Float16 ph = (_Float16)p;
            s += (float)ph;                        // sum quantized p
            afrag[t] = ph;
        }
#pragma unroll
        for (int nb = 0; nb < 8; ++nb)
            acc[nb] = __builtin_amdgcn_mfma_f32_16x16x32_f16(afrag, bf[nb], acc[nb], 0, 0, 0);
    };

    loadV(0, bf0, w0a, w0b);
    __syncthreads();                   // fmask DMA drained (vmcnt0 in barrier)

    for (int ss = 0; ss < NSS; ss += 2) {
        loadV(ss + 1, bf1, w1a, w1b);
        compute(ss, bf0, w0a, w0b);
        int kn = (ss + 2 < NSS) ? ss + 2 : NSS - 1;   // clamped redundant tail load
        loadV(kn, bf0, w0a, w0b);
        compute(ss + 1, bf1, w1a, w1b);
    }

    // ---- row sums for this wave's ksteps (rows rg..rg+15) ----
    s += __shfl_xor(s, 16, 64);
    s += __shfl_xor(s, 32, 64);

    __syncthreads();                   // all waves done reading fmask LDS

    // ---- combine kstep-parity pairs; accs overlay on fmask LDS (16 KB) ----
    float* accp = (float*)lds;   // [32][128]
    if (half == 0) {
#pragma unroll
        for (int nb = 0; nb < 8; ++nb)
#pragma unroll
            for (int reg = 0; reg < 4; ++reg)
                accp[(rg + quad * 4 + reg) * 128 + nb * 16 + m] = acc[nb][reg];
        if (lane < 16) rsums[rg + lane] = s;
    }
    __syncthreads();
    if (half == 1) {
#pragma unroll
        for (int nb = 0; nb < 8; ++nb)
#pragma unroll
            for (int reg = 0; reg < 4; ++reg)
                accp[(rg + quad * 4 + reg) * 128 + nb * 16 + m] += acc[nb][reg];
        if (lane < 16) rsums[rg + lane] += s;
    }
    __syncthreads();

    // ---- normalize, ELU, store fp32 (32 x 128) ----
    for (int o = threadIdx.x; o < 32 * 128; o += 256) {
        int lr = o >> 7, n = o & 127;
        float v = accp[lr * 128 + n];
        float rs = rsums[lr];
        rs = (rs > 0.f) ? rs : 1.f;
        float h = v / rs;
        float ov = (h > 0.f) ? h : (fast_exp2(h * LOG2E) - 1.f);
        out[(size_t)(i0 + lr) * OUT_F + n] = ov;
    }
}

// ---------------------------------------------------------------------------
extern "C" void kernel_launch(void* const* d_in, const int* in_sizes, int n_in,
                              void* d_out, int out_size, void* d_ws, size_t ws_size,
                              hipStream_t stream) {
    const float* node_emb = (const float*)d_in[0];  // fp32 [20000,512]
    const float* attr_emb = (const float*)d_in[1];  // fp32 [5000,512]
    const int*   feat     = (const int*)d_in[2];    // int32 [20000,5000]
    const float* W        = (const float*)d_in[3];  // fp32 [512,128]
    const float* a        = (const float*)d_in[4];  // fp32 [256,1]
    float*       out      = (float*)d_out;          // fp32 [20000,128]

    char* ws = (char*)d_ws;
    float*    Wa1 = (float*)(ws + 0);          // 512 f32
    float*    Wa2 = (float*)(ws + 4096);       // 512 f32
    float*    wh1 = (float*)(ws + 8192);       // 20000 f32 (ends 88192)
    float*    wh2 = (float*)(ws + 90112);      // 5376 f32 incl. NEGBIG pad (ends 111616)
    float*    mx  = (float*)(ws + 111616);     // 1 f32
    _Float16* Wp  = (_Float16*)(ws + 131072);  // 65536 f16 (ends 262144)
    _Float16* Vp  = (_Float16*)(ws + 262144);  // 5120*128 f16 (ends 1572864)
    unsigned* fmk = (unsigned*)(ws + 2097152); // 20000*160 u32 = 12.8 MB (ends ~14.9 MB)

    prep_kernel<<<64, 256, 0, stream>>>(W, a, Wa1, Wa2, Wp);
    wh_kernel<<<6250, 256, 0, stream>>>(node_emb, attr_emb, Wa1, Wa2, wh1, wh2);
    max_kernel<<<1, 256, 0, stream>>>(wh2, mx);
    attr_h_kernel<<<320, 64, 0, stream>>>(attr_emb, Wp, Vp);
    pack_kernel<<<12500, 256, 0, stream>>>(feat, fmk);
    attn_kernel<<<625, 256, 0, stream>>>(fmk, wh1, wh2, mx, Vp, out);
}